// Round 11
// baseline (292.594 us; speedup 1.0000x reference)
//
#include <hip/hip_runtime.h>

#define T_TOT  512
#define TCH    256                 // t-chunk per LDS pass
#define NCHUNK (T_TOT / TCH)
#define DTC    0.1f

// Wave64 inclusive add-scan via __shfl_up (ds_bpermute). Chosen over the
// 6-op DPP sequence for first-bench correctness certainty: plain HIP
// intrinsic, explicit guard, no ctrl/mask conventions to get wrong. With
// R=4 thread coarsening only 6 wave-scans/chunk/wave remain, so the extra
// LDS-pipe cost (~11 us/CU aggregate) stays hidden under ~48 us of VMEM.
__device__ __forceinline__ float wave_iscan_add(float x) {
#pragma unroll
    for (int off = 1; off < 64; off <<= 1) {
        const float u = __shfl_up(x, off);
        x += (((threadIdx.x & 63) >= off) ? u : 0.0f);
    }
    return x;
}

// One block per batch. 256 threads = 4 waves; each wave scans 3 of the 12
// (vehicle,coord) chains. Each lane owns 4 consecutive timesteps (R=4
// thread coarsening): serial local cumsum in registers + ONE wave scan per
// chain per chunk. LDS staging is channel-major: stage accesses are
// lane-stride-1 (conflict-free) and scan accesses are contiguous b128.
__global__ __launch_bounds__(256, 4) void motion_scan_kernel(
    const float* __restrict__ acc,    // [B, T, 12]
    const float* __restrict__ init,   // [B, 4] : p0x p0y v0x v0y (vehicle 0)
    float* __restrict__ out)          // [B, T, 24] : per veh {px,py,vx,vy}
{
    __shared__ __align__(16) float sa[12 * TCH];   // input chunk, channel-major
    __shared__ __align__(16) float so[24 * TCH];   // output chunk, channel-major

    const int b    = blockIdx.x;
    const int tid  = threadIdx.x;
    const int lane = tid & 63;
    const int wave = tid >> 6;

    const size_t in_base  = (size_t)b * T_TOT * 12;
    const size_t out_base = (size_t)b * T_TOT * 24;

    // Per-wave chain setup: wave w owns chains 3w..3w+2 (chain = veh*2+coord).
    float p0[3], v0c[3];
    int   chp[3];                     // output channel for p; v is chp+2
#pragma unroll
    for (int k = 0; k < 3; ++k) {
        const int ch = wave * 3 + k;
        const int nv = ch >> 1, c = ch & 1;
        chp[k] = nv * 4 + c;
        if (ch < 2) {                 // vehicle 0 gets initial_states
            p0[k]  = init[b * 4 + c];
            v0c[k] = init[b * 4 + 2 + c];
        } else {
            p0[k] = 0.0f; v0c[k] = 0.0f;
        }
    }
    float Sc[3] = {0.f, 0.f, 0.f};    // carry of cumsum(a)
    float Wc[3] = {0.f, 0.f, 0.f};    // carry of cumsum(S)

    const float dt2 = DTC * DTC;

    for (int chunk = 0; chunk < NCHUNK; ++chunk) {
        // ---- load: thread tid owns t-row tid of this chunk (12 floats) ----
        {
            const float4* g = (const float4*)(acc + in_base +
                               (size_t)(chunk * TCH + tid) * 12);
            const float4 r0 = g[0], r1 = g[1], r2 = g[2];
            const float rr[12] = { r0.x, r0.y, r0.z, r0.w,
                                   r1.x, r1.y, r1.z, r1.w,
                                   r2.x, r2.y, r2.z, r2.w };
#pragma unroll
            for (int ch = 0; ch < 12; ++ch)
                sa[ch * TCH + tid] = rr[ch];    // lane-stride-1: conflict-free
        }
        __syncthreads();

        // ---- scan: each wave, 3 chains; lane owns t = 4*lane .. 4*lane+3 ----
        const int t0 = lane * 4;
#pragma unroll
        for (int k = 0; k < 3; ++k) {
            const int ch = wave * 3 + k;
            const float4 a4 = *(const float4*)&sa[ch * TCH + t0]; // ds_read_b128

            // local inclusive cumsum s_i and its cumsum w_i (registers)
            const float s0 = a4.x, s1 = s0 + a4.y, s2 = s1 + a4.z, s3 = s2 + a4.w;
            const float w0 = s0, w1 = w0 + s1, w2 = w1 + s2, w3 = w2 + s3;

            // cross-thread: scan of per-thread totals
            const float incS = wave_iscan_add(s3);
            const float base = Sc[k] + (incS - s3);        // S offset for lane
            const float TW   = 4.0f * base + w3;           // lane's sum of S_i
            const float incW = wave_iscan_add(TW);
            const float Q    = Wc[k] + (incW - TW);        // W offset for lane

            // global S_i = base + s_i ; W_i = Q + (i+1)*base + w_i
            const float S0g = base + s0, S1g = base + s1,
                        S2g = base + s2, S3g = base + s3;
            const float v0k = v0c[k], p0k = p0[k];
            const int   tg  = chunk * TCH + t0;            // global t of elem 0

            float4 vv, pp;
            vv.x = fmaf(DTC, S0g, v0k);
            vv.y = fmaf(DTC, S1g, v0k);
            vv.z = fmaf(DTC, S2g, v0k);
            vv.w = fmaf(DTC, S3g, v0k);
            pp.x = fmaf(DTC * (float)(tg + 1), v0k, p0k)
                 + dt2 * (Q + 1.0f * base + w0 + 0.5f * S0g);
            pp.y = fmaf(DTC * (float)(tg + 2), v0k, p0k)
                 + dt2 * (Q + 2.0f * base + w1 + 0.5f * S1g);
            pp.z = fmaf(DTC * (float)(tg + 3), v0k, p0k)
                 + dt2 * (Q + 3.0f * base + w2 + 0.5f * S2g);
            pp.w = fmaf(DTC * (float)(tg + 4), v0k, p0k)
                 + dt2 * (Q + 4.0f * base + w3 + 0.5f * S3g);

            *(float4*)&so[ chp[k]      * TCH + t0] = pp;   // ds_write_b128
            *(float4*)&so[(chp[k] + 2) * TCH + t0] = vv;

            Sc[k] += __shfl(incS, 63);                     // carry to next chunk
            Wc[k] += __shfl(incW, 63);
        }
        __syncthreads();

        // ---- store: thread tid writes contiguous 24-float output row ----
        {
            float rr[24];
#pragma unroll
            for (int cho = 0; cho < 24; ++cho)
                rr[cho] = so[cho * TCH + tid];             // lane-stride-1
            float4* g = (float4*)(out + out_base +
                         (size_t)(chunk * TCH + tid) * 24);
#pragma unroll
            for (int q = 0; q < 6; ++q)
                g[q] = make_float4(rr[q*4], rr[q*4+1], rr[q*4+2], rr[q*4+3]);
        }
        __syncthreads();   // protect sa/so before next chunk's load/scan
    }
}

extern "C" void kernel_launch(void* const* d_in, const int* in_sizes, int n_in,
                              void* d_out, int out_size, void* d_ws, size_t ws_size,
                              hipStream_t stream) {
    const float* acc  = (const float*)d_in[0];   // [B, 512, 12]
    const float* init = (const float*)d_in[1];   // [B, 4]
    float* out = (float*)d_out;                  // [B, 512, 24]

    const int B = in_sizes[0] / (T_TOT * 12);    // 4096
    motion_scan_kernel<<<dim3(B), dim3(256), 0, stream>>>(acc, init, out);
}